// Round 20
// baseline (360.578 us; speedup 1.0000x reference)
//
#include <hip/hip_runtime.h>
#include <math.h>

#define BATCH 8
#define SEQ   2048
#define CDIM  768
#define HDIM  64
#define QROWS 32
#define NSB   (SEQ / 64)
#define MARGIN 1e-2f
// exact: (raw * -1e14) * 0.125 == raw * (-1e14 * 0.125) (pow-2 scale commutes w/ rounding)
#define MASKC (-99999999999999.0 * 0.125)

// ---------------------------------------------------------------- projection
// 512 blocks x 32 rows, 2 rows x 4 dims/thread, DOUBLE-BUFFERED LDS staged via
// __builtin_amdgcn_global_load_lds (direct DMA, no VGPR round-trip, no spill):
// 2-phase schedule ISSUE(next) -> COMPUTE(cur) -> barrier hides global latency
// under the fp64 compute phase (r14-r19: serial barrier-fenced staging capped
// VALUBusy at 55%). W staging is naturally linear in lane order (m104 constraint).
#define GLL(GP, LP) __builtin_amdgcn_global_load_lds(                          \
    (const __attribute__((address_space(1))) void*)(GP),                       \
    (__attribute__((address_space(3))) void*)(LP), 16, 0, 0)

__global__ __launch_bounds__(256) void qkv_proj_kernel(
    const float* __restrict__ x,
    const float* __restrict__ Wk,
    const float* __restrict__ Wq,
    const float* __restrict__ Wv,
    double* __restrict__ qd,
    double* __restrict__ kd,
    float*  __restrict__ vf,
    unsigned* __restrict__ wcount)
{
    __shared__ __align__(16) float xs[2][32][64];    // linear [row][c]
    __shared__ __align__(16) float wqs[2][64 * 64];
    __shared__ __align__(16) float wks[2][64 * 64];
    __shared__ __align__(16) float wvs[2][64 * 64];

    const int tid = threadIdx.x;
    if (blockIdx.x == 0 && tid == 0) *wcount = 0u;
    const int tx  = tid & 15;        // dims 4tx..4tx+3
    const int ty  = tid >> 4;        // rows 2ty, 2ty+1
    const size_t row0 = (size_t)blockIdx.x * 32;

    double qa[2][4] = {{0, 0, 0, 0}, {0, 0, 0, 0}};
    double ka[2][4] = {{0, 0, 0, 0}, {0, 0, 0, 0}};
    float  va[2][4] = {{0, 0, 0, 0}, {0, 0, 0, 0}};

#define ISSUE(BUF, CC) do {                                                    \
    const int wb = (tid & 192);          /* wave base (uniform per wave) */    \
    _Pragma("unroll")                                                          \
    for (int it = 0; it < 2; ++it) {                                           \
        const int t = tid + it * 256;    /* x float4 index 0..511 */           \
        GLL(&x[(row0 + (t >> 4)) * CDIM + (CC) + (t & 15) * 4],                \
            &xs[BUF][0][0] + (size_t)(it * 256 + wb) * 4);                     \
    }                                                                          \
    const float4* wqg = reinterpret_cast<const float4*>(&Wq[(size_t)(CC) * HDIM]); \
    const float4* wkg = reinterpret_cast<const float4*>(&Wk[(size_t)(CC) * HDIM]); \
    const float4* wvg = reinterpret_cast<const float4*>(&Wv[(size_t)(CC) * HDIM]); \
    _Pragma("unroll")                                                          \
    for (int it = 0; it < 4; ++it) {                                           \
        const int t  = tid + it * 256;   /* W float4 index 0..1023 */          \
        const int lb = (it * 256 + wb) * 4;                                    \
        GLL(wqg + t, &wqs[BUF][0] + lb);                                       \
        GLL(wkg + t, &wks[BUF][0] + lb);                                       \
        GLL(wvg + t, &wvs[BUF][0] + lb);                                       \
    }                                                                          \
} while (0)

    ISSUE(0, 0);
    __syncthreads();                 // vmcnt(0) drain -> buf0 ready

    int buf = 0;
    for (int cc = 0; cc < CDIM; cc += 64) {
        if (cc + 64 < CDIM) ISSUE(buf ^ 1, cc + 64);   // in flight during compute

        #pragma unroll 4
        for (int c = 0; c < 64; ++c) {
            const float4 wq4 = *reinterpret_cast<const float4*>(&wqs[buf][c * 64 + tx * 4]);
            const float4 wk4 = *reinterpret_cast<const float4*>(&wks[buf][c * 64 + tx * 4]);
            const float4 wv4 = *reinterpret_cast<const float4*>(&wvs[buf][c * 64 + tx * 4]);
            #pragma unroll
            for (int i = 0; i < 2; ++i) {
                const float  xv = xs[buf][2 * ty + i][c];
                const double xd = (double)xv;
                qa[i][0] += xd * (double)wq4.x;
                qa[i][1] += xd * (double)wq4.y;
                qa[i][2] += xd * (double)wq4.z;
                qa[i][3] += xd * (double)wq4.w;
                ka[i][0] += xd * (double)wk4.x;
                ka[i][1] += xd * (double)wk4.y;
                ka[i][2] += xd * (double)wk4.z;
                ka[i][3] += xd * (double)wk4.w;
                va[i][0] += xv * wv4.x;
                va[i][1] += xv * wv4.y;
                va[i][2] += xv * wv4.z;
                va[i][3] += xv * wv4.w;
            }
        }
        __syncthreads();             // drains prefetch (already landed) + frees buf
        buf ^= 1;
    }

    #pragma unroll
    for (int i = 0; i < 2; ++i) {
        const size_t row = row0 + ty * 2 + i;
        *reinterpret_cast<double2*>(&qd[row * HDIM + tx * 4])     = make_double2(qa[i][0], qa[i][1]);
        *reinterpret_cast<double2*>(&qd[row * HDIM + tx * 4 + 2]) = make_double2(qa[i][2], qa[i][3]);
        *reinterpret_cast<double2*>(&kd[row * HDIM + tx * 4])     = make_double2(ka[i][0], ka[i][1]);
        *reinterpret_cast<double2*>(&kd[row * HDIM + tx * 4 + 2]) = make_double2(ka[i][2], ka[i][3]);
        *reinterpret_cast<float4*>(&vf[row * HDIM + tx * 4]) =
            make_float4(va[i][0], va[i][1], va[i][2], va[i][3]);
    }
#undef ISSUE
}

// ---------------------------------------------------------------- argmin engine
// r13/r14/r16/r19-proven 256-thread version (2 rows x 4 cols/thread), unchanged.
__device__ __forceinline__ unsigned long long rowcap_mask(
    float a0, float a1, float a2, float a3,
    int rg, int sb, int tx, unsigned gsh, float& mrun)
{
    a0 = (sb * 64 + tx      > rg) ? a0 : 3.0e38f;   // FUTURE only
    a1 = (sb * 64 + 16 + tx > rg) ? a1 : 3.0e38f;
    a2 = (sb * 64 + 32 + tx > rg) ? a2 : 3.0e38f;
    a3 = (sb * 64 + 48 + tx > rg) ? a3 : 3.0e38f;
    float tmin = fminf(fminf(a0, a1), fminf(a2, a3));
    #pragma unroll
    for (int off = 8; off > 0; off >>= 1)
        tmin = fminf(tmin, __shfl_xor(tmin, off, 16));
    mrun = fminf(mrun, tmin);
    const float thr = mrun + MARGIN;
    // sentinel guard: masked entries (3e38) must never be captured, even when
    // thr saturates to 3e38 (row with no future cols seen yet) — r12 bug.
    const unsigned long long b0 = __ballot((a0 <= thr) && (a0 < 3.0e37f));
    const unsigned long long b1 = __ballot((a1 <= thr) && (a1 < 3.0e37f));
    const unsigned long long b2 = __ballot((a2 <= thr) && (a2 < 3.0e37f));
    const unsigned long long b3 = __ballot((a3 <= thr) && (a3 < 3.0e37f));
    return ((b0 >> gsh) & 0xFFFFull)
         | (((b1 >> gsh) & 0xFFFFull) << 16)
         | (((b2 >> gsh) & 0xFFFFull) << 32)
         | (((b3 >> gsh) & 0xFFFFull) << 48);
}

#define STAGE(KF, SB)                                                          \
    { const double* ksrc = kd + ((size_t)b * SEQ + (size_t)(SB) * 64) * HDIM;  \
      _Pragma("unroll")                                                        \
      for (int it = 0; it < 8; ++it) {                                         \
          const int r = rb + it * 8;                                           \
          const double2 v2 = *reinterpret_cast<const double2*>(                \
              &ksrc[(size_t)r * HDIM + 2 * c2]);                               \
          KF[r][2 * c2]     = (float)v2.x;                                     \
          KF[r][2 * c2 + 1] = (float)v2.y; } }

#define BODY(KF, SB)                                                           \
    { float s00 = 0.f, s01 = 0.f, s02 = 0.f, s03 = 0.f;                        \
      float s10 = 0.f, s11 = 0.f, s12 = 0.f, s13 = 0.f;                        \
      _Pragma("unroll")                                                        \
      for (int d4 = 0; d4 < 16; ++d4) {                                        \
          const float4 q0 = *reinterpret_cast<const float4*>(&qf[2 * ty][4 * d4]);     \
          const float4 q1 = *reinterpret_cast<const float4*>(&qf[2 * ty + 1][4 * d4]); \
          const float4 k0 = *reinterpret_cast<const float4*>(&KF[tx][4 * d4]);         \
          const float4 k1 = *reinterpret_cast<const float4*>(&KF[16 + tx][4 * d4]);    \
          const float4 k2 = *reinterpret_cast<const float4*>(&KF[32 + tx][4 * d4]);    \
          const float4 k3 = *reinterpret_cast<const float4*>(&KF[48 + tx][4 * d4]);    \
          s00 += q0.x*k0.x + q0.y*k0.y + q0.z*k0.z + q0.w*k0.w;                \
          s01 += q0.x*k1.x + q0.y*k1.y + q0.z*k1.z + q0.w*k1.w;                \
          s02 += q0.x*k2.x + q0.y*k2.y + q0.z*k2.z + q0.w*k2.w;                \
          s03 += q0.x*k3.x + q0.y*k3.y + q0.z*k3.z + q0.w*k3.w;                \
          s10 += q1.x*k0.x + q1.y*k0.y + q1.z*k0.z + q1.w*k0.w;                \
          s11 += q1.x*k1.x + q1.y*k1.y + q1.z*k1.z + q1.w*k1.w;                \
          s12 += q1.x*k2.x + q1.y*k2.y + q1.z*k2.z + q1.w*k2.w;                \
          s13 += q1.x*k3.x + q1.y*k3.y + q1.z*k3.z + q1.w*k3.w;                \
      }                                                                        \
      const unsigned long long m0 =                                            \
          rowcap_mask(s00, s01, s02, s03, r0 + 2 * ty,     (SB), tx, gsh, mrun0); \
      const unsigned long long m1 =                                            \
          rowcap_mask(s10, s11, s12, s13, r0 + 2 * ty + 1, (SB), tx, gsh, mrun1); \
      if (tx == 0) {                                                           \
          candmask[2 * ty][(SB)]     = m0;                                     \
          candmask[2 * ty + 1][(SB)] = m1; } }

__global__ __launch_bounds__(256) void argmin_kernel(
    const double* __restrict__ qd,
    const double* __restrict__ kd,
    const float*  __restrict__ vf,
    float* __restrict__ out,
    unsigned* __restrict__ wcount,
    unsigned* __restrict__ wlist)
{
    __shared__ float qf[QROWS][68];
    __shared__ float kfA[64][68];
    __shared__ float kfB[64][68];
    __shared__ unsigned long long candmask[QROWS][NSB];

    const int tid  = threadIdx.x;
    const int lane = tid & 63;
    const unsigned gsh = (unsigned)(lane & 48);   // 16-lane group base in ballot
    const int tx  = tid & 15;       // score cols 16j + tx (consecutive -> conflict-free)
    const int ty  = tid >> 4;       // score rows 2ty, 2ty+1
    const int b   = blockIdx.x;     // batch == XCD (gridDim.x = 8)
    const int byy = blockIdx.y;
    const int tb  = (byy < 32) ? byy : 95 - byy;   // co-CU pair work ~constant
    const int r0  = tb * QROWS;
    const int sb0 = tb >> 1;        // first s-block containing any future col

    // stage qf (fp64 -> fp32, coalesced)
    {
        const double* qsrc = qd + ((size_t)b * SEQ + r0) * HDIM;
        #pragma unroll
        for (int it = 0; it < 8; ++it) {
            const int idx = tid + it * 256;
            qf[idx >> 6][idx & 63] = (float)qsrc[(idx >> 6) * HDIM + (idx & 63)];
        }
    }

    const int c2 = tid & 31;
    const int rb = tid >> 5;

    float mrun0 = 3.0e38f, mrun1 = 3.0e38f;

    STAGE(kfA, sb0);
    __syncthreads();

    int sb = sb0;
    while (true) {
        if (sb + 1 < NSB) STAGE(kfB, sb + 1);
        BODY(kfA, sb);
        __syncthreads();
        ++sb;
        if (sb >= NSB) break;
        if (sb + 1 < NSB) STAGE(kfA, sb + 1);
        BODY(kfB, sb);
        __syncthreads();
        ++sb;
        if (sb >= NSB) break;
    }
    __syncthreads();

    // ---- refinement: 8 lanes per row walk the bitmasks, exact fp64 dots
    const int row = tid >> 3, l8 = tid & 7;
    const int rg  = r0 + row;
    int n = 0;
    double min1 = 1.0e300, min2 = 1.0e300;
    int amin = -1;
    const double* qrow = qd + ((size_t)b * SEQ + rg) * HDIM;
    for (int sbi = sb0; sbi < NSB; ++sbi) {
        unsigned long long m = candmask[row][sbi];
        while (m) {
            const int p = __ffsll((long long)m) - 1;
            m &= m - 1;
            const int col = sbi * 64 + p;
            if (col <= rg) continue;          // defense in depth: FUTURE only
            ++n;
            const double* krow = kd + ((size_t)b * SEQ + col) * HDIM;
            double part = 0.0;
            #pragma unroll
            for (int dd = 0; dd < 8; ++dd)
                part += qrow[8 * l8 + dd] * krow[8 * l8 + dd];
            #pragma unroll
            for (int off = 4; off > 0; off >>= 1)
                part += __shfl_xor(part, off, 8);
            if (part < min1) { min2 = min1; min1 = part; amin = col; }
            else if (part < min2) { min2 = part; }
        }
    }
    // honest (no sufficiently-negative future / empty future) or ambiguous tie
    // -> append to exact-row worklist; exact_kernel writes those rows.
    const bool flag = (n == 0) || (min1 > -1e-10) || ((min2 - min1) < 1e-11);
    float* orow = out + ((size_t)b * SEQ + rg) * HDIM;
    if (flag) {
        if (l8 == 0) {
            const unsigned slot = atomicAdd(wcount, 1u);
            wlist[slot] = ((unsigned)b << 16) | (unsigned)rg;
        }
    } else {
        const float* vrow = vf + ((size_t)b * SEQ + amin) * HDIM;
        const float4 v0 = *reinterpret_cast<const float4*>(&vrow[8 * l8]);
        const float4 v1 = *reinterpret_cast<const float4*>(&vrow[8 * l8 + 4]);
        *reinterpret_cast<float4*>(&orow[8 * l8])     = v0;
        *reinterpret_cast<float4*>(&orow[8 * l8 + 4]) = v1;
    }
}

// ---------------------------------------------------------------- exact-row fallback
// Grid-strides the flagged-row worklist (~2-4 rows/batch). r16/r19-proven.
__global__ __launch_bounds__(256) void exact_kernel(
    const double* __restrict__ qd,
    const double* __restrict__ kd,
    const float*  __restrict__ vf,
    float* __restrict__ out,
    const unsigned* __restrict__ wcount,
    const unsigned* __restrict__ wlist)
{
    __shared__ double qs[HDIM];
    __shared__ double lgbuf[SEQ];
    __shared__ float  pbuf[SEQ];
    __shared__ float  outacc[4][HDIM];
    __shared__ double mred[4];
    __shared__ float  psred[4];

    const int tid  = threadIdx.x;
    const int wid  = tid >> 6, lane = tid & 63;
    const unsigned nflag = *wcount;

    for (unsigned i = blockIdx.x; i < nflag; i += gridDim.x) {
        const unsigned e = wlist[i];
        const int b  = (int)(e >> 16);
        const int rg = (int)(e & 0xFFFFu);
        float* orow = out + ((size_t)b * SEQ + rg) * HDIM;

        if (tid < HDIM) qs[tid] = qd[((size_t)b * SEQ + rg) * HDIM + tid];
        __syncthreads();

        const double qv = qs[lane];
        const double* kb = kd + (size_t)b * SEQ * HDIM;
        const int cbase = 512 * wid;

        for (int cc = 0; cc < 512; cc += 4) {
            const int c = cbase + cc;
            double p0 = kb[(size_t)(c + 0) * HDIM + lane] * qv;
            double p1 = kb[(size_t)(c + 1) * HDIM + lane] * qv;
            double p2 = kb[(size_t)(c + 2) * HDIM + lane] * qv;
            double p3 = kb[(size_t)(c + 3) * HDIM + lane] * qv;
            #pragma unroll
            for (int off = 32; off > 0; off >>= 1) {
                p0 += __shfl_xor(p0, off, 64);
                p1 += __shfl_xor(p1, off, 64);
                p2 += __shfl_xor(p2, off, 64);
                p3 += __shfl_xor(p3, off, 64);
            }
            if (lane == 0) {
                lgbuf[c]     = p0 * ((c     <= rg) ? 0.125 : MASKC);
                lgbuf[c + 1] = p1 * ((c + 1 <= rg) ? 0.125 : MASKC);
                lgbuf[c + 2] = p2 * ((c + 2 <= rg) ? 0.125 : MASKC);
                lgbuf[c + 3] = p3 * ((c + 3 <= rg) ? 0.125 : MASKC);
            }
        }
        __syncthreads();

        double mymax = -1.0e300;
        #pragma unroll
        for (int it = 0; it < 8; ++it)
            mymax = fmax(mymax, lgbuf[tid + it * 256]);
        #pragma unroll
        for (int off = 32; off > 0; off >>= 1)
            mymax = fmax(mymax, __shfl_xor(mymax, off, 64));
        if (lane == 0) mred[wid] = mymax;
        __syncthreads();
        const double M = fmax(fmax(mred[0], mred[1]), fmax(mred[2], mred[3]));

        float mypsum = 0.f;
        #pragma unroll
        for (int it = 0; it < 8; ++it) {
            const int col = tid + it * 256;
            const double dl = lgbuf[col] - M;
            const float p = (dl < -80.0) ? 0.f : (float)exp(dl);
            pbuf[col] = p;
            mypsum += p;
        }
        #pragma unroll
        for (int off = 32; off > 0; off >>= 1)
            mypsum += __shfl_xor(mypsum, off, 64);
        if (lane == 0) psred[wid] = mypsum;
        __syncthreads();
        const float PS = psred[0] + psred[1] + psred[2] + psred[3];

        const int d = tid & 63, chunk = tid >> 6;
        float acc = 0.f;
        for (int cc = 0; cc < 512; ++cc) {
            const int col = chunk * 512 + cc;
            acc += pbuf[col] * vf[((size_t)b * SEQ + col) * HDIM + d];
        }
        outacc[chunk][d] = acc;
        __syncthreads();
        if (tid < HDIM)
            orow[tid] = (outacc[0][tid] + outacc[1][tid] +
                         outacc[2][tid] + outacc[3][tid]) / PS;
        __syncthreads();   // buffers reused next worklist entry
    }
}

extern "C" void kernel_launch(void* const* d_in, const int* in_sizes, int n_in,
                              void* d_out, int out_size, void* d_ws, size_t ws_size,
                              hipStream_t stream)
{
    const float* x  = (const float*)d_in[0];
    const float* Wk = (const float*)d_in[1];
    const float* Wq = (const float*)d_in[2];
    const float* Wv = (const float*)d_in[3];
    float* out = (float*)d_out;

    // workspace: q fp64 (8MB) | k fp64 (8MB) | v fp32 (4MB) | wcount | wlist (64KB)
    double* qd = (double*)d_ws;
    double* kd = qd + (size_t)BATCH * SEQ * HDIM;
    float*  vf = (float*)(kd + (size_t)BATCH * SEQ * HDIM);
    unsigned* wcount = (unsigned*)(vf + (size_t)BATCH * SEQ * HDIM);
    unsigned* wlist  = wcount + 16;   // 64B-aligned

    qkv_proj_kernel<<<dim3(512), dim3(256), 0, stream>>>(x, Wk, Wq, Wv, qd, kd, vf, wcount);
    argmin_kernel<<<dim3(8, 64), dim3(256), 0, stream>>>(qd, kd, vf, out, wcount, wlist);
    exact_kernel<<<dim3(128), dim3(256), 0, stream>>>(qd, kd, vf, out, wcount, wlist);
}

// Round 21
// 325.897 us; speedup vs baseline: 1.1064x; 1.1064x over previous
//
#include <hip/hip_runtime.h>
#include <math.h>

#define BATCH 8
#define SEQ   2048
#define CDIM  768
#define HDIM  64
#define QROWS 32
#define NSB   (SEQ / 64)
#define MARGIN 1e-2f
// exact: (raw * -1e14) * 0.125 == raw * (-1e14 * 0.125) (pow-2 scale commutes w/ rounding)
#define MASKC (-99999999999999.0 * 0.125)

// ---------------------------------------------------------------- projection
// r16/r19-proven optimum: 256 blocks x 64 rows, 4 rows x 4 dims per thread,
// x staged transposed. 131.9 us — the structural plateau (ledger: r14 133.5,
// r17 small-chunk 151, r18 reg-prefetch 188+spill, r20 gload_lds-dbuf 172).
__global__ __launch_bounds__(256) void qkv_proj_kernel(
    const float* __restrict__ x,
    const float* __restrict__ Wk,
    const float* __restrict__ Wq,
    const float* __restrict__ Wv,
    double* __restrict__ qd,
    double* __restrict__ kd,
    float*  __restrict__ vf,
    unsigned* __restrict__ wcount)
{
    __shared__ float xsT[64][68];    // [c][row]
    __shared__ float wqs[64 * 64];
    __shared__ float wks[64 * 64];
    __shared__ float wvs[64 * 64];

    const int tid = threadIdx.x;
    if (blockIdx.x == 0 && tid == 0) *wcount = 0u;
    const int tx  = tid & 15;        // dims 4tx..4tx+3
    const int ty  = tid >> 4;        // rows 4ty..4ty+3
    const size_t row0 = (size_t)blockIdx.x * 64;

    double qa[4][4] = {{0,0,0,0},{0,0,0,0},{0,0,0,0},{0,0,0,0}};
    double ka[4][4] = {{0,0,0,0},{0,0,0,0},{0,0,0,0},{0,0,0,0}};
    float  va[4][4] = {{0,0,0,0},{0,0,0,0},{0,0,0,0},{0,0,0,0}};

    for (int cc = 0; cc < CDIM; cc += 64) {
        __syncthreads();
        #pragma unroll
        for (int it = 0; it < 4; ++it) {
            const int t  = tid + it * 256;
            const int r  = t >> 4;
            const int c4 = t & 15;
            const float4 v4 = *reinterpret_cast<const float4*>(
                &x[(row0 + r) * CDIM + cc + c4 * 4]);
            xsT[4 * c4 + 0][r] = v4.x;
            xsT[4 * c4 + 1][r] = v4.y;
            xsT[4 * c4 + 2][r] = v4.z;
            xsT[4 * c4 + 3][r] = v4.w;
        }
        {
            const float4* wqg = reinterpret_cast<const float4*>(&Wq[(size_t)cc * HDIM]);
            const float4* wkg = reinterpret_cast<const float4*>(&Wk[(size_t)cc * HDIM]);
            const float4* wvg = reinterpret_cast<const float4*>(&Wv[(size_t)cc * HDIM]);
            float4* wql = reinterpret_cast<float4*>(wqs);
            float4* wkl = reinterpret_cast<float4*>(wks);
            float4* wvl = reinterpret_cast<float4*>(wvs);
            #pragma unroll
            for (int it = 0; it < 4; ++it) {
                const int t = tid + it * 256;
                wql[t] = wqg[t];
                wkl[t] = wkg[t];
                wvl[t] = wvg[t];
            }
        }
        __syncthreads();
        #pragma unroll 4
        for (int c = 0; c < 64; ++c) {
            const float4 xv  = *reinterpret_cast<const float4*>(&xsT[c][4 * ty]);
            const float4 wq4 = *reinterpret_cast<const float4*>(&wqs[c * 64 + tx * 4]);
            const float4 wk4 = *reinterpret_cast<const float4*>(&wks[c * 64 + tx * 4]);
            const float4 wv4 = *reinterpret_cast<const float4*>(&wvs[c * 64 + tx * 4]);
            const double xd0 = (double)xv.x, xd1 = (double)xv.y;
            const double xd2 = (double)xv.z, xd3 = (double)xv.w;
            qa[0][0] += xd0 * (double)wq4.x; qa[0][1] += xd0 * (double)wq4.y;
            qa[0][2] += xd0 * (double)wq4.z; qa[0][3] += xd0 * (double)wq4.w;
            qa[1][0] += xd1 * (double)wq4.x; qa[1][1] += xd1 * (double)wq4.y;
            qa[1][2] += xd1 * (double)wq4.z; qa[1][3] += xd1 * (double)wq4.w;
            qa[2][0] += xd2 * (double)wq4.x; qa[2][1] += xd2 * (double)wq4.y;
            qa[2][2] += xd2 * (double)wq4.z; qa[2][3] += xd2 * (double)wq4.w;
            qa[3][0] += xd3 * (double)wq4.x; qa[3][1] += xd3 * (double)wq4.y;
            qa[3][2] += xd3 * (double)wq4.z; qa[3][3] += xd3 * (double)wq4.w;
            ka[0][0] += xd0 * (double)wk4.x; ka[0][1] += xd0 * (double)wk4.y;
            ka[0][2] += xd0 * (double)wk4.z; ka[0][3] += xd0 * (double)wk4.w;
            ka[1][0] += xd1 * (double)wk4.x; ka[1][1] += xd1 * (double)wk4.y;
            ka[1][2] += xd1 * (double)wk4.z; ka[1][3] += xd1 * (double)wk4.w;
            ka[2][0] += xd2 * (double)wk4.x; ka[2][1] += xd2 * (double)wk4.y;
            ka[2][2] += xd2 * (double)wk4.z; ka[2][3] += xd2 * (double)wk4.w;
            ka[3][0] += xd3 * (double)wk4.x; ka[3][1] += xd3 * (double)wk4.y;
            ka[3][2] += xd3 * (double)wk4.z; ka[3][3] += xd3 * (double)wk4.w;
            va[0][0] += xv.x * wv4.x; va[0][1] += xv.x * wv4.y;
            va[0][2] += xv.x * wv4.z; va[0][3] += xv.x * wv4.w;
            va[1][0] += xv.y * wv4.x; va[1][1] += xv.y * wv4.y;
            va[1][2] += xv.y * wv4.z; va[1][3] += xv.y * wv4.w;
            va[2][0] += xv.z * wv4.x; va[2][1] += xv.z * wv4.y;
            va[2][2] += xv.z * wv4.z; va[2][3] += xv.z * wv4.w;
            va[3][0] += xv.w * wv4.x; va[3][1] += xv.w * wv4.y;
            va[3][2] += xv.w * wv4.z; va[3][3] += xv.w * wv4.w;
        }
    }
    #pragma unroll
    for (int i = 0; i < 4; ++i) {
        const size_t row = row0 + 4 * ty + i;
        *reinterpret_cast<double2*>(&qd[row * HDIM + tx * 4])     = make_double2(qa[i][0], qa[i][1]);
        *reinterpret_cast<double2*>(&qd[row * HDIM + tx * 4 + 2]) = make_double2(qa[i][2], qa[i][3]);
        *reinterpret_cast<double2*>(&kd[row * HDIM + tx * 4])     = make_double2(ka[i][0], ka[i][1]);
        *reinterpret_cast<double2*>(&kd[row * HDIM + tx * 4 + 2]) = make_double2(ka[i][2], ka[i][3]);
        *reinterpret_cast<float4*>(&vf[row * HDIM + tx * 4]) =
            make_float4(va[i][0], va[i][1], va[i][2], va[i][3]);
    }
}

// ---------------------------------------------------------------- argmin engine
// r13/r14/r16/r19-proven 256-thread version (2 rows x 4 cols/thread), unchanged.
__device__ __forceinline__ unsigned long long rowcap_mask(
    float a0, float a1, float a2, float a3,
    int rg, int sb, int tx, unsigned gsh, float& mrun)
{
    a0 = (sb * 64 + tx      > rg) ? a0 : 3.0e38f;   // FUTURE only
    a1 = (sb * 64 + 16 + tx > rg) ? a1 : 3.0e38f;
    a2 = (sb * 64 + 32 + tx > rg) ? a2 : 3.0e38f;
    a3 = (sb * 64 + 48 + tx > rg) ? a3 : 3.0e38f;
    float tmin = fminf(fminf(a0, a1), fminf(a2, a3));
    #pragma unroll
    for (int off = 8; off > 0; off >>= 1)
        tmin = fminf(tmin, __shfl_xor(tmin, off, 16));
    mrun = fminf(mrun, tmin);
    const float thr = mrun + MARGIN;
    // sentinel guard: masked entries (3e38) must never be captured, even when
    // thr saturates to 3e38 (row with no future cols seen yet) — r12 bug.
    const unsigned long long b0 = __ballot((a0 <= thr) && (a0 < 3.0e37f));
    const unsigned long long b1 = __ballot((a1 <= thr) && (a1 < 3.0e37f));
    const unsigned long long b2 = __ballot((a2 <= thr) && (a2 < 3.0e37f));
    const unsigned long long b3 = __ballot((a3 <= thr) && (a3 < 3.0e37f));
    return ((b0 >> gsh) & 0xFFFFull)
         | (((b1 >> gsh) & 0xFFFFull) << 16)
         | (((b2 >> gsh) & 0xFFFFull) << 32)
         | (((b3 >> gsh) & 0xFFFFull) << 48);
}

#define STAGE(KF, SB)                                                          \
    { const double* ksrc = kd + ((size_t)b * SEQ + (size_t)(SB) * 64) * HDIM;  \
      _Pragma("unroll")                                                        \
      for (int it = 0; it < 8; ++it) {                                         \
          const int r = rb + it * 8;                                           \
          const double2 v2 = *reinterpret_cast<const double2*>(                \
              &ksrc[(size_t)r * HDIM + 2 * c2]);                               \
          KF[r][2 * c2]     = (float)v2.x;                                     \
          KF[r][2 * c2 + 1] = (float)v2.y; } }

#define BODY(KF, SB)                                                           \
    { float s00 = 0.f, s01 = 0.f, s02 = 0.f, s03 = 0.f;                        \
      float s10 = 0.f, s11 = 0.f, s12 = 0.f, s13 = 0.f;                        \
      _Pragma("unroll")                                                        \
      for (int d4 = 0; d4 < 16; ++d4) {                                        \
          const float4 q0 = *reinterpret_cast<const float4*>(&qf[2 * ty][4 * d4]);     \
          const float4 q1 = *reinterpret_cast<const float4*>(&qf[2 * ty + 1][4 * d4]); \
          const float4 k0 = *reinterpret_cast<const float4*>(&KF[tx][4 * d4]);         \
          const float4 k1 = *reinterpret_cast<const float4*>(&KF[16 + tx][4 * d4]);    \
          const float4 k2 = *reinterpret_cast<const float4*>(&KF[32 + tx][4 * d4]);    \
          const float4 k3 = *reinterpret_cast<const float4*>(&KF[48 + tx][4 * d4]);    \
          s00 += q0.x*k0.x + q0.y*k0.y + q0.z*k0.z + q0.w*k0.w;                \
          s01 += q0.x*k1.x + q0.y*k1.y + q0.z*k1.z + q0.w*k1.w;                \
          s02 += q0.x*k2.x + q0.y*k2.y + q0.z*k2.z + q0.w*k2.w;                \
          s03 += q0.x*k3.x + q0.y*k3.y + q0.z*k3.z + q0.w*k3.w;                \
          s10 += q1.x*k0.x + q1.y*k0.y + q1.z*k0.z + q1.w*k0.w;                \
          s11 += q1.x*k1.x + q1.y*k1.y + q1.z*k1.z + q1.w*k1.w;                \
          s12 += q1.x*k2.x + q1.y*k2.y + q1.z*k2.z + q1.w*k2.w;                \
          s13 += q1.x*k3.x + q1.y*k3.y + q1.z*k3.z + q1.w*k3.w;                \
      }                                                                        \
      const unsigned long long m0 =                                            \
          rowcap_mask(s00, s01, s02, s03, r0 + 2 * ty,     (SB), tx, gsh, mrun0); \
      const unsigned long long m1 =                                            \
          rowcap_mask(s10, s11, s12, s13, r0 + 2 * ty + 1, (SB), tx, gsh, mrun1); \
      if (tx == 0) {                                                           \
          candmask[2 * ty][(SB)]     = m0;                                     \
          candmask[2 * ty + 1][(SB)] = m1; } }

__global__ __launch_bounds__(256) void argmin_kernel(
    const double* __restrict__ qd,
    const double* __restrict__ kd,
    const float*  __restrict__ vf,
    float* __restrict__ out,
    unsigned* __restrict__ wcount,
    unsigned* __restrict__ wlist)
{
    __shared__ float qf[QROWS][68];
    __shared__ float kfA[64][68];
    __shared__ float kfB[64][68];
    __shared__ unsigned long long candmask[QROWS][NSB];

    const int tid  = threadIdx.x;
    const int lane = tid & 63;
    const unsigned gsh = (unsigned)(lane & 48);   // 16-lane group base in ballot
    const int tx  = tid & 15;       // score cols 16j + tx (consecutive -> conflict-free)
    const int ty  = tid >> 4;       // score rows 2ty, 2ty+1
    const int b   = blockIdx.x;     // batch == XCD (gridDim.x = 8)
    const int byy = blockIdx.y;
    const int tb  = (byy < 32) ? byy : 95 - byy;   // co-CU pair work ~constant
    const int r0  = tb * QROWS;
    const int sb0 = tb >> 1;        // first s-block containing any future col

    // stage qf (fp64 -> fp32, coalesced)
    {
        const double* qsrc = qd + ((size_t)b * SEQ + r0) * HDIM;
        #pragma unroll
        for (int it = 0; it < 8; ++it) {
            const int idx = tid + it * 256;
            qf[idx >> 6][idx & 63] = (float)qsrc[(idx >> 6) * HDIM + (idx & 63)];
        }
    }

    const int c2 = tid & 31;
    const int rb = tid >> 5;

    float mrun0 = 3.0e38f, mrun1 = 3.0e38f;

    STAGE(kfA, sb0);
    __syncthreads();

    int sb = sb0;
    while (true) {
        if (sb + 1 < NSB) STAGE(kfB, sb + 1);
        BODY(kfA, sb);
        __syncthreads();
        ++sb;
        if (sb >= NSB) break;
        if (sb + 1 < NSB) STAGE(kfA, sb + 1);
        BODY(kfB, sb);
        __syncthreads();
        ++sb;
        if (sb >= NSB) break;
    }
    __syncthreads();

    // ---- refinement: 8 lanes per row walk the bitmasks, exact fp64 dots
    const int row = tid >> 3, l8 = tid & 7;
    const int rg  = r0 + row;
    int n = 0;
    double min1 = 1.0e300, min2 = 1.0e300;
    int amin = -1;
    const double* qrow = qd + ((size_t)b * SEQ + rg) * HDIM;
    for (int sbi = sb0; sbi < NSB; ++sbi) {
        unsigned long long m = candmask[row][sbi];
        while (m) {
            const int p = __ffsll((long long)m) - 1;
            m &= m - 1;
            const int col = sbi * 64 + p;
            if (col <= rg) continue;          // defense in depth: FUTURE only
            ++n;
            const double* krow = kd + ((size_t)b * SEQ + col) * HDIM;
            double part = 0.0;
            #pragma unroll
            for (int dd = 0; dd < 8; ++dd)
                part += qrow[8 * l8 + dd] * krow[8 * l8 + dd];
            #pragma unroll
            for (int off = 4; off > 0; off >>= 1)
                part += __shfl_xor(part, off, 8);
            if (part < min1) { min2 = min1; min1 = part; amin = col; }
            else if (part < min2) { min2 = part; }
        }
    }
    // honest (no sufficiently-negative future / empty future) or ambiguous tie
    // -> append to exact-row worklist; exact_kernel writes those rows.
    const bool flag = (n == 0) || (min1 > -1e-10) || ((min2 - min1) < 1e-11);
    float* orow = out + ((size_t)b * SEQ + rg) * HDIM;
    if (flag) {
        if (l8 == 0) {
            const unsigned slot = atomicAdd(wcount, 1u);
            wlist[slot] = ((unsigned)b << 16) | (unsigned)rg;
        }
    } else {
        const float* vrow = vf + ((size_t)b * SEQ + amin) * HDIM;
        const float4 v0 = *reinterpret_cast<const float4*>(&vrow[8 * l8]);
        const float4 v1 = *reinterpret_cast<const float4*>(&vrow[8 * l8 + 4]);
        *reinterpret_cast<float4*>(&orow[8 * l8])     = v0;
        *reinterpret_cast<float4*>(&orow[8 * l8 + 4]) = v1;
    }
}

// ---------------------------------------------------------------- exact-row fallback
// Grid-strides the flagged-row worklist (~2-4 rows/batch). r16/r19-proven.
__global__ __launch_bounds__(256) void exact_kernel(
    const double* __restrict__ qd,
    const double* __restrict__ kd,
    const float*  __restrict__ vf,
    float* __restrict__ out,
    const unsigned* __restrict__ wcount,
    const unsigned* __restrict__ wlist)
{
    __shared__ double qs[HDIM];
    __shared__ double lgbuf[SEQ];
    __shared__ float  pbuf[SEQ];
    __shared__ float  outacc[4][HDIM];
    __shared__ double mred[4];
    __shared__ float  psred[4];

    const int tid  = threadIdx.x;
    const int wid  = tid >> 6, lane = tid & 63;
    const unsigned nflag = *wcount;

    for (unsigned i = blockIdx.x; i < nflag; i += gridDim.x) {
        const unsigned e = wlist[i];
        const int b  = (int)(e >> 16);
        const int rg = (int)(e & 0xFFFFu);
        float* orow = out + ((size_t)b * SEQ + rg) * HDIM;

        if (tid < HDIM) qs[tid] = qd[((size_t)b * SEQ + rg) * HDIM + tid];
        __syncthreads();

        const double qv = qs[lane];
        const double* kb = kd + (size_t)b * SEQ * HDIM;
        const int cbase = 512 * wid;

        for (int cc = 0; cc < 512; cc += 4) {
            const int c = cbase + cc;
            double p0 = kb[(size_t)(c + 0) * HDIM + lane] * qv;
            double p1 = kb[(size_t)(c + 1) * HDIM + lane] * qv;
            double p2 = kb[(size_t)(c + 2) * HDIM + lane] * qv;
            double p3 = kb[(size_t)(c + 3) * HDIM + lane] * qv;
            #pragma unroll
            for (int off = 32; off > 0; off >>= 1) {
                p0 += __shfl_xor(p0, off, 64);
                p1 += __shfl_xor(p1, off, 64);
                p2 += __shfl_xor(p2, off, 64);
                p3 += __shfl_xor(p3, off, 64);
            }
            if (lane == 0) {
                lgbuf[c]     = p0 * ((c     <= rg) ? 0.125 : MASKC);
                lgbuf[c + 1] = p1 * ((c + 1 <= rg) ? 0.125 : MASKC);
                lgbuf[c + 2] = p2 * ((c + 2 <= rg) ? 0.125 : MASKC);
                lgbuf[c + 3] = p3 * ((c + 3 <= rg) ? 0.125 : MASKC);
            }
        }
        __syncthreads();

        double mymax = -1.0e300;
        #pragma unroll
        for (int it = 0; it < 8; ++it)
            mymax = fmax(mymax, lgbuf[tid + it * 256]);
        #pragma unroll
        for (int off = 32; off > 0; off >>= 1)
            mymax = fmax(mymax, __shfl_xor(mymax, off, 64));
        if (lane == 0) mred[wid] = mymax;
        __syncthreads();
        const double M = fmax(fmax(mred[0], mred[1]), fmax(mred[2], mred[3]));

        float mypsum = 0.f;
        #pragma unroll
        for (int it = 0; it < 8; ++it) {
            const int col = tid + it * 256;
            const double dl = lgbuf[col] - M;
            const float p = (dl < -80.0) ? 0.f : (float)exp(dl);
            pbuf[col] = p;
            mypsum += p;
        }
        #pragma unroll
        for (int off = 32; off > 0; off >>= 1)
            mypsum += __shfl_xor(mypsum, off, 64);
        if (lane == 0) psred[wid] = mypsum;
        __syncthreads();
        const float PS = psred[0] + psred[1] + psred[2] + psred[3];

        const int d = tid & 63, chunk = tid >> 6;
        float acc = 0.f;
        for (int cc = 0; cc < 512; ++cc) {
            const int col = chunk * 512 + cc;
            acc += pbuf[col] * vf[((size_t)b * SEQ + col) * HDIM + d];
        }
        outacc[chunk][d] = acc;
        __syncthreads();
        if (tid < HDIM)
            orow[tid] = (outacc[0][tid] + outacc[1][tid] +
                         outacc[2][tid] + outacc[3][tid]) / PS;
        __syncthreads();   // buffers reused next worklist entry
    }
}

extern "C" void kernel_launch(void* const* d_in, const int* in_sizes, int n_in,
                              void* d_out, int out_size, void* d_ws, size_t ws_size,
                              hipStream_t stream)
{
    const float* x  = (const float*)d_in[0];
    const float* Wk = (const float*)d_in[1];
    const float* Wq = (const float*)d_in[2];
    const float* Wv = (const float*)d_in[3];
    float* out = (float*)d_out;

    // workspace: q fp64 (8MB) | k fp64 (8MB) | v fp32 (4MB) | wcount | wlist (64KB)
    double* qd = (double*)d_ws;
    double* kd = qd + (size_t)BATCH * SEQ * HDIM;
    float*  vf = (float*)(kd + (size_t)BATCH * SEQ * HDIM);
    unsigned* wcount = (unsigned*)(vf + (size_t)BATCH * SEQ * HDIM);
    unsigned* wlist  = wcount + 16;   // 64B-aligned

    qkv_proj_kernel<<<dim3(256), dim3(256), 0, stream>>>(x, Wk, Wq, Wv, qd, kd, vf, wcount);
    argmin_kernel<<<dim3(8, 64), dim3(256), 0, stream>>>(qd, kd, vf, out, wcount, wlist);
    exact_kernel<<<dim3(128), dim3(256), 0, stream>>>(qd, kd, vf, out, wcount, wlist);
}